// Round 8
// baseline (1154.290 us; speedup 1.0000x reference)
//
#include <hip/hip_runtime.h>
#include <math.h>

// ---------------------------------------------------------------------------
// OP3 Physics Network forward, fp32. Sizes: B=32,L=32,N=8,D=256,A=16,AENC=32,EFF=32
// Tokens: BLN = 8192 node tokens, pairs = 8192*7.
// Key restructure: pairs@pw_w1 = U[i]+V[j] with U=senc@W1top+b1, V=senc@W1bot.
// Round 8: (a) full revert of round-7's wave remap (it cut UNIQUE LDS bytes
// but cost is GROSS lane-bytes — m134's 85 B/cy is gross; broadcast doesn't
// discount. 290->330us, falsified). (b) pint + ie/ia GEMMs move to gemm16_k:
// 128 threads, 128x128 tile, 8x16 microtile -> gross LDS = 0.375 B/FLOP
// (vs 0.5 for 8x8) -> LDS ceiling ~90% FMA (was ~66%). 128 acc + staging
// stays < 256 VGPR (no spill possible); LDS 33.8KB -> 4 blocks/CU x 2 waves.
// Same grids (448x2 / 448x4), same loads-at-loop-top structure (nothing
// held across the FMA block — rounds 4/5/6 proved held staging regs spill).
// UV stays on the round-3-exact gemm128_k (VGPR 84 proven).
// ---------------------------------------------------------------------------

#define BLN 8192
#define BL  1024

__device__ __forceinline__ float eluf(float x)  { return x > 0.0f ? x : expm1f(x); }
__device__ __forceinline__ float sigmf_(float x){ return 1.0f / (1.0f + expf(-x)); }

// ---------------------------------------------------------------------------
// Generic tiled GEMM: C[M,N] = act(A[M,K] @ W[K,N] + bias) [* rowscale[row]]
// 64x64 tile, BK=32, 256 threads, 4x4 per thread. Single-buffered LDS.
// ROUND-2 PROVEN FORM (tr/tc row-band mapping).
// ---------------------------------------------------------------------------
template<int ACT, bool ROWSCALE, bool PAIRGATHER>
__global__ __launch_bounds__(256) void gemm_k(
    const float* __restrict__ A, int lda,
    const float* __restrict__ W, int ldw,
    const float* __restrict__ bias,
    float* __restrict__ C, int ldc,
    int K,
    const float* __restrict__ rowscale,
    const float* __restrict__ Vm, int jj)
{
  __shared__ float As[32][68];   // k-major, padded
  __shared__ float Ws[32][64];   // k-major (natural)
  const int m0 = blockIdx.x * 64;
  const int n0 = blockIdx.y * 64;
  const int tid = threadIdx.x;

  const int arow = tid >> 2;            // 0..63
  const int akg  = (tid & 3) << 3;      // 0,8,16,24
  const int wrow = tid >> 3;            // 0..31
  const int wcg  = (tid & 7) << 3;      // 0..56

  const int tr = (tid >> 4) << 2;       // 0..60
  const int tc = (tid & 15) << 2;       // 0..60

  const int gr = m0 + arow;
  const float* aptr;
  const float* vptr = nullptr;
  if (PAIRGATHER) {
    const int jjv = (jj >= 0) ? jj : (gr >> 13);
    const int r = gr & (BLN - 1);
    const int i = r & 7;
    const int j = jjv + ((jjv >= i) ? 1 : 0);
    const int vr = (r & ~7) | j;
    aptr = A  + (size_t)r * lda + akg;
    vptr = Vm + (size_t)vr * lda + akg;
  } else {
    aptr = A + (size_t)gr * lda + akg;
  }
  const float* wptr = W + (size_t)wrow * ldw + n0 + wcg;

  float acc[4][4] = {};

  for (int k0 = 0; k0 < K; k0 += 32) {
    float av[8];
    if (PAIRGATHER) {
      float4 u0 = *(const float4*)(aptr + k0);
      float4 u1 = *(const float4*)(aptr + k0 + 4);
      float4 v0 = *(const float4*)(vptr + k0);
      float4 v1 = *(const float4*)(vptr + k0 + 4);
      av[0]=eluf(u0.x+v0.x); av[1]=eluf(u0.y+v0.y); av[2]=eluf(u0.z+v0.z); av[3]=eluf(u0.w+v0.w);
      av[4]=eluf(u1.x+v1.x); av[5]=eluf(u1.y+v1.y); av[6]=eluf(u1.z+v1.z); av[7]=eluf(u1.w+v1.w);
    } else {
      float4 a0 = *(const float4*)(aptr + k0);
      float4 a1 = *(const float4*)(aptr + k0 + 4);
      av[0]=a0.x; av[1]=a0.y; av[2]=a0.z; av[3]=a0.w;
      av[4]=a1.x; av[5]=a1.y; av[6]=a1.z; av[7]=a1.w;
    }
    float4 w0 = *(const float4*)(wptr + (size_t)k0 * ldw);
    float4 w1 = *(const float4*)(wptr + (size_t)k0 * ldw + 4);

    __syncthreads();   // previous tile fully consumed before overwrite
#pragma unroll
    for (int i = 0; i < 8; ++i) As[akg + i][arow] = av[i];
    *(float4*)&Ws[wrow][wcg]     = w0;
    *(float4*)&Ws[wrow][wcg + 4] = w1;
    __syncthreads();

#pragma unroll
    for (int k = 0; k < 32; ++k) {
      float4 a = *(const float4*)&As[k][tr];
      float4 w = *(const float4*)&Ws[k][tc];
      acc[0][0] += a.x*w.x; acc[0][1] += a.x*w.y; acc[0][2] += a.x*w.z; acc[0][3] += a.x*w.w;
      acc[1][0] += a.y*w.x; acc[1][1] += a.y*w.y; acc[1][2] += a.y*w.z; acc[1][3] += a.y*w.w;
      acc[2][0] += a.z*w.x; acc[2][1] += a.z*w.y; acc[2][2] += a.z*w.z; acc[2][3] += a.z*w.w;
      acc[3][0] += a.w*w.x; acc[3][1] += a.w*w.y; acc[3][2] += a.w*w.z; acc[3][3] += a.w*w.w;
    }
  }

  float bv[4] = {0.f, 0.f, 0.f, 0.f};
  if (bias) {
    float4 b = *(const float4*)(bias + n0 + tc);
    bv[0]=b.x; bv[1]=b.y; bv[2]=b.z; bv[3]=b.w;
  }
#pragma unroll
  for (int i = 0; i < 4; ++i) {
    const int r = m0 + tr + i;
    float v0 = acc[i][0] + bv[0];
    float v1 = acc[i][1] + bv[1];
    float v2 = acc[i][2] + bv[2];
    float v3 = acc[i][3] + bv[3];
    if (ACT == 1) { v0=eluf(v0); v1=eluf(v1); v2=eluf(v2); v3=eluf(v3); }
    else if (ACT == 2) { v0=sigmf_(v0); v1=sigmf_(v1); v2=sigmf_(v2); v3=sigmf_(v3); }
    if (ROWSCALE) { float s = rowscale[r]; v0*=s; v1*=s; v2*=s; v3*=s; }
    float4 o; o.x=v0; o.y=v1; o.z=v2; o.w=v3;
    *(float4*)&C[(size_t)r * ldc + n0 + tc] = o;
  }
}

// ---------------------------------------------------------------------------
// Big GEMM (UV only): 128x128 tile, BK=32, 256 threads, 8x8 per thread.
// EXACT ROUND-3 BODY (proven VGPR=84, no spill): loads at loop top before
// barrier-1, nothing held across the FMA block. launch_bounds(256,3).
// ---------------------------------------------------------------------------
template<int ACT, bool PAIRGATHER>
__global__ __launch_bounds__(256, 3) void gemm128_k(
    const float* __restrict__ A, int lda,
    const float* __restrict__ W, int ldw,
    const float* __restrict__ bias,
    float* __restrict__ C, int ldc,
    int K,
    const float* __restrict__ Vm)
{
  __shared__ float As[32][132];
  __shared__ float Ws[32][132];
  const int m0 = blockIdx.x * 128;
  const int n0 = blockIdx.y * 128;
  const int tid = threadIdx.x;

  const int arow = tid >> 1;            // 0..127
  const int ak16 = (tid & 1) << 4;      // 0,16
  const int wrow = tid >> 3;            // 0..31
  const int wcg  = (tid & 7) << 4;      // 0..112

  const int ty4 = (tid >> 4) << 2;      // 0..60
  const int tx4 = (tid & 15) << 2;      // 0..60

  const int gr = m0 + arow;
  const float* aptr;
  const float* vptr = nullptr;
  if (PAIRGATHER) {
    const int jjv = gr >> 13;
    const int r = gr & (BLN - 1);
    const int i = r & 7;
    const int j = jjv + ((jjv >= i) ? 1 : 0);
    const int vr = (r & ~7) | j;
    aptr = A  + (size_t)r * lda + ak16;
    vptr = Vm + (size_t)vr * lda + ak16;
  } else {
    aptr = A + (size_t)gr * lda + ak16;
  }
  const float* wptr = W + (size_t)wrow * ldw + n0 + wcg;

  float acc[8][8] = {};

  for (int k0 = 0; k0 < K; k0 += 32) {
    float4 ua[4], va[4], wa[4];
#pragma unroll
    for (int q = 0; q < 4; ++q) ua[q] = *(const float4*)(aptr + k0 + 4*q);
    if (PAIRGATHER) {
#pragma unroll
      for (int q = 0; q < 4; ++q) va[q] = *(const float4*)(vptr + k0 + 4*q);
    }
#pragma unroll
    for (int q = 0; q < 4; ++q) wa[q] = *(const float4*)(wptr + (size_t)k0 * ldw + 4*q);

    __syncthreads();
#pragma unroll
    for (int q = 0; q < 4; ++q) {
      float4 u = ua[q];
      if (PAIRGATHER) {
        float4 v = va[q];
        u.x = eluf(u.x+v.x); u.y = eluf(u.y+v.y); u.z = eluf(u.z+v.z); u.w = eluf(u.w+v.w);
      }
      As[ak16 + 4*q + 0][arow] = u.x;
      As[ak16 + 4*q + 1][arow] = u.y;
      As[ak16 + 4*q + 2][arow] = u.z;
      As[ak16 + 4*q + 3][arow] = u.w;
    }
#pragma unroll
    for (int q = 0; q < 4; ++q)
      *(float4*)&Ws[wrow][wcg + 4*q] = wa[q];
    __syncthreads();

#pragma unroll
    for (int k = 0; k < 32; ++k) {
      float4 a0 = *(const float4*)&As[k][ty4];
      float4 a1 = *(const float4*)&As[k][64 + ty4];
      float4 w0 = *(const float4*)&Ws[k][tx4];
      float4 w1 = *(const float4*)&Ws[k][64 + tx4];
      float ar[8] = {a0.x,a0.y,a0.z,a0.w,a1.x,a1.y,a1.z,a1.w};
      float wr[8] = {w0.x,w0.y,w0.z,w0.w,w1.x,w1.y,w1.z,w1.w};
#pragma unroll
      for (int i = 0; i < 8; ++i) {
#pragma unroll
        for (int j = 0; j < 8; ++j) acc[i][j] += ar[i] * wr[j];
      }
    }
  }

  float bv[8] = {0.f,0.f,0.f,0.f,0.f,0.f,0.f,0.f};
  if (bias) {
    float4 b0 = *(const float4*)(bias + n0 + tx4);
    float4 b1 = *(const float4*)(bias + n0 + 64 + tx4);
    bv[0]=b0.x; bv[1]=b0.y; bv[2]=b0.z; bv[3]=b0.w;
    bv[4]=b1.x; bv[5]=b1.y; bv[6]=b1.z; bv[7]=b1.w;
  }
#pragma unroll
  for (int ih = 0; ih < 2; ++ih) {
#pragma unroll
    for (int i = 0; i < 4; ++i) {
      const int r = m0 + ih*64 + ty4 + i;
#pragma unroll
      for (int jh = 0; jh < 2; ++jh) {
        float v0 = acc[ih*4+i][jh*4+0] + bv[jh*4+0];
        float v1 = acc[ih*4+i][jh*4+1] + bv[jh*4+1];
        float v2 = acc[ih*4+i][jh*4+2] + bv[jh*4+2];
        float v3 = acc[ih*4+i][jh*4+3] + bv[jh*4+3];
        if (ACT == 1) { v0=eluf(v0); v1=eluf(v1); v2=eluf(v2); v3=eluf(v3); }
        else if (ACT == 2) { v0=sigmf_(v0); v1=sigmf_(v1); v2=sigmf_(v2); v3=sigmf_(v3); }
        float4 o; o.x=v0; o.y=v1; o.z=v2; o.w=v3;
        *(float4*)&C[(size_t)r * ldc + n0 + jh*64 + tx4] = o;
      }
    }
  }
}

// ---------------------------------------------------------------------------
// High-reuse GEMM (pint + ie/ia): 128x128 tile, BK=32, 128 threads (2 waves),
// 8x16 microtile -> gross LDS read = 0.375 B/FLOP (vs 0.5 for 8x8).
// 128 acc + staging < 256 VGPR: cannot spill. LDS 33.8KB -> 4 blocks/CU.
// Staging: each thread loads one full A row-slice (8 float4) and one
// 32-float W row-chunk (8 float4). Loads at loop top; nothing held across
// the FMA block. Reads conflict-free (8-chunk span = all 32 banks).
// PAIRGATHER: A_virtual[r,k] = elu(U[r,k] + V[vrow(r),k]); jj from row>>13.
// ---------------------------------------------------------------------------
template<int ACT, bool PAIRGATHER>
__global__ __launch_bounds__(128) void gemm16_k(
    const float* __restrict__ A, int lda,
    const float* __restrict__ W, int ldw,
    const float* __restrict__ bias,
    float* __restrict__ C, int ldc,
    int K,
    const float* __restrict__ Vm)
{
  __shared__ float As[32][132];
  __shared__ float Ws[32][132];
  const int m0 = blockIdx.x * 128;
  const int n0 = blockIdx.y * 128;
  const int tid = threadIdx.x;          // 0..127

  // staging roles
  const int arow = tid;                 // 0..127: full BK-row per thread
  const int wrow = tid >> 2;            // 0..31
  const int wcg  = (tid & 3) << 5;      // 0,32,64,96

  // compute roles: 16x8 thread grid; thread owns rows {ty4+i, 64+ty4+i},
  // cols {tx4+32j .. +3} for j=0..3
  const int ty4 = (tid >> 3) << 2;      // 0..60
  const int tx4 = (tid & 7) << 2;       // 0..28

  const int gr = m0 + arow;
  const float* aptr;
  const float* vptr = nullptr;
  if (PAIRGATHER) {
    const int jjv = gr >> 13;
    const int r = gr & (BLN - 1);
    const int i = r & 7;
    const int j = jjv + ((jjv >= i) ? 1 : 0);
    const int vr = (r & ~7) | j;
    aptr = A  + (size_t)r * lda;
    vptr = Vm + (size_t)vr * lda;
  } else {
    aptr = A + (size_t)gr * lda;
  }
  const float* wptr = W + (size_t)wrow * ldw + n0 + wcg;

  float acc[8][16] = {};

  for (int k0 = 0; k0 < K; k0 += 32) {
    float4 ua[8], va[8], wa[8];
#pragma unroll
    for (int q = 0; q < 8; ++q) ua[q] = *(const float4*)(aptr + k0 + 4*q);
    if (PAIRGATHER) {
#pragma unroll
      for (int q = 0; q < 8; ++q) va[q] = *(const float4*)(vptr + k0 + 4*q);
    }
#pragma unroll
    for (int q = 0; q < 8; ++q) wa[q] = *(const float4*)(wptr + (size_t)k0 * ldw + 4*q);

    __syncthreads();   // previous tile fully consumed before overwrite
#pragma unroll
    for (int q = 0; q < 8; ++q) {
      float4 u = ua[q];
      if (PAIRGATHER) {
        float4 v = va[q];
        u.x = eluf(u.x+v.x); u.y = eluf(u.y+v.y); u.z = eluf(u.z+v.z); u.w = eluf(u.w+v.w);
      }
      As[4*q + 0][arow] = u.x;
      As[4*q + 1][arow] = u.y;
      As[4*q + 2][arow] = u.z;
      As[4*q + 3][arow] = u.w;
    }
#pragma unroll
    for (int q = 0; q < 8; ++q)
      *(float4*)&Ws[wrow][wcg + 4*q] = wa[q];
    __syncthreads();

#pragma unroll
    for (int k = 0; k < 32; ++k) {
      float4 a0 = *(const float4*)&As[k][ty4];
      float4 a1 = *(const float4*)&As[k][64 + ty4];
      float4 w0 = *(const float4*)&Ws[k][tx4];
      float4 w1 = *(const float4*)&Ws[k][32 + tx4];
      float4 w2 = *(const float4*)&Ws[k][64 + tx4];
      float4 w3 = *(const float4*)&Ws[k][96 + tx4];
      float ar[8]  = {a0.x,a0.y,a0.z,a0.w,a1.x,a1.y,a1.z,a1.w};
      float wr[16] = {w0.x,w0.y,w0.z,w0.w,w1.x,w1.y,w1.z,w1.w,
                      w2.x,w2.y,w2.z,w2.w,w3.x,w3.y,w3.z,w3.w};
#pragma unroll
      for (int i = 0; i < 8; ++i) {
#pragma unroll
        for (int j = 0; j < 16; ++j) acc[i][j] += ar[i] * wr[j];
      }
    }
  }

  float bv[16];
#pragma unroll
  for (int jg = 0; jg < 4; ++jg) {
    if (bias) {
      float4 b = *(const float4*)(bias + n0 + jg*32 + tx4);
      bv[jg*4+0]=b.x; bv[jg*4+1]=b.y; bv[jg*4+2]=b.z; bv[jg*4+3]=b.w;
    } else {
      bv[jg*4+0]=0.f; bv[jg*4+1]=0.f; bv[jg*4+2]=0.f; bv[jg*4+3]=0.f;
    }
  }
#pragma unroll
  for (int ih = 0; ih < 2; ++ih) {
#pragma unroll
    for (int i = 0; i < 4; ++i) {
      const int r = m0 + ih*64 + ty4 + i;
#pragma unroll
      for (int jg = 0; jg < 4; ++jg) {
        float v0 = acc[ih*4+i][jg*4+0] + bv[jg*4+0];
        float v1 = acc[ih*4+i][jg*4+1] + bv[jg*4+1];
        float v2 = acc[ih*4+i][jg*4+2] + bv[jg*4+2];
        float v3 = acc[ih*4+i][jg*4+3] + bv[jg*4+3];
        if (ACT == 1) { v0=eluf(v0); v1=eluf(v1); v2=eluf(v2); v3=eluf(v3); }
        else if (ACT == 2) { v0=sigmf_(v0); v1=sigmf_(v1); v2=sigmf_(v2); v3=sigmf_(v3); }
        float4 o; o.x=v0; o.y=v1; o.z=v2; o.w=v3;
        *(float4*)&C[(size_t)r * ldc + n0 + jg*32 + tx4] = o;
      }
    }
  }
}

// ---------------------------------------------------------------------------
// Action-encoder MLP: one block per (b,l) token. one_hot @ w1 == w1[a].
// ---------------------------------------------------------------------------
__global__ __launch_bounds__(256) void ae_kernel(
    const int* __restrict__ action,
    const float* __restrict__ w1, const float* __restrict__ b1,
    const float* __restrict__ w2, const float* __restrict__ b2,
    float* __restrict__ aenc)
{
  __shared__ float hs[256];
  const int bl = blockIdx.x;
  const int t = threadIdx.x;
  const int a = action[bl];
  hs[t] = eluf(w1[a * 256 + t] + b1[t]);
  __syncthreads();
  if (t < 32) {
    float acc = 0.f;
    for (int k = 0; k < 256; ++k) acc += hs[k] * w2[k * 32 + t];
    aenc[bl * 32 + t] = eluf(acc + b2[t]);
  }
}

// fill sa2[:, 256:288] with broadcast aenc
__global__ __launch_bounds__(256) void sa_fill_kernel(const float* __restrict__ aenc,
                                                      float* __restrict__ sa2)
{
  const int idx = blockIdx.x * 256 + threadIdx.x;  // 8192*32
  const int r = idx >> 5, c = idx & 31;
  sa2[(size_t)r * 288 + 256 + c] = aenc[(r >> 3) * 32 + c];
}

// zero sa2[:, 256:288] (serial fallback path only)
__global__ __launch_bounds__(256) void zero_teff_kernel(float* __restrict__ sa2)
{
  const int idx = blockIdx.x * 256 + threadIdx.x;
  const int r = idx >> 5, c = idx & 31;
  sa2[(size_t)r * 288 + 256 + c] = 0.f;
}

// s_att[row] = sigmoid(dot(h_ea[row,256:512], aat_w2) + aat_b2). 4 rows/block.
__global__ __launch_bounds__(256) void satt_kernel(
    const float* __restrict__ hea, const float* __restrict__ w,
    const float* __restrict__ b, float* __restrict__ satt)
{
  const int wv = threadIdx.x >> 6;
  const int lane = threadIdx.x & 63;
  const int row = blockIdx.x * 4 + wv;
  const float* h = hea + (size_t)row * 512 + 256;
  float acc = 0.f;
#pragma unroll
  for (int m = 0; m < 4; ++m) acc += h[lane + 64 * m] * w[lane + 64 * m];
#pragma unroll
  for (int off = 32; off; off >>= 1) acc += __shfl_xor(acc, off, 64);
  if (lane == 0) satt[row] = sigmf_(acc + b[0]);
}

// ie/ia layer-2 + p_eff*p_att + accumulate (serial fallback). 8 rows/block.
__global__ __launch_bounds__(256) void pair_l2_kernel(
    const float* __restrict__ h,
    const float* __restrict__ ie_w2, const float* __restrict__ ie_b2,
    const float* __restrict__ ia_w2, const float* __restrict__ ia_b2,
    float* __restrict__ sa2)
{
  __shared__ float hs[8][512];
  __shared__ float pas[8];
  const int r0 = blockIdx.x * 8;
  const int tid = threadIdx.x;
#pragma unroll
  for (int it = 0; it < 4; ++it) {
    const int f4 = it * 256 + tid;
    const int rr = f4 >> 7;
    const int cc = (f4 & 127) << 2;
    *(float4*)&hs[rr][cc] = *(const float4*)&h[(size_t)(r0 + rr) * 512 + cc];
  }
  __syncthreads();
  const int row = tid >> 5;
  const int col = tid & 31;
  float pa = 0.f;
#pragma unroll
  for (int m = 0; m < 8; ++m) pa += hs[row][256 + col + 32 * m] * ia_w2[col + 32 * m];
#pragma unroll
  for (int off = 16; off; off >>= 1) pa += __shfl_xor(pa, off, 64);
  if (col == 0) pas[row] = sigmf_(pa + ia_b2[0]);
  float acc = 0.f;
  for (int k = 0; k < 256; ++k) acc += hs[row][k] * ie_w2[k * 32 + col];
  __syncthreads();
  const float val = eluf(acc + ie_b2[col]) * pas[row];
  sa2[(size_t)(r0 + row) * 288 + 256 + col] += val;
}

// Batched variant: h is [7*8192, 512]; loop jj internally, accumulate in regs.
__global__ __launch_bounds__(256) void pair_l2_all_kernel(
    const float* __restrict__ h,
    const float* __restrict__ ie_w2, const float* __restrict__ ie_b2,
    const float* __restrict__ ia_w2, const float* __restrict__ ia_b2,
    float* __restrict__ sa2)
{
  __shared__ float hs[8][512];
  __shared__ float pas[8];
  const int r0 = blockIdx.x * 8;
  const int tid = threadIdx.x;
  const int row = tid >> 5;
  const int col = tid & 31;
  float teff = 0.f;
  for (int jj = 0; jj < 7; ++jj) {
    __syncthreads();
    const float* hb = h + ((size_t)jj * BLN + r0) * 512;
#pragma unroll
    for (int it = 0; it < 4; ++it) {
      const int f4 = it * 256 + tid;
      const int rr = f4 >> 7;
      const int cc = (f4 & 127) << 2;
      *(float4*)&hs[rr][cc] = *(const float4*)&hb[(size_t)rr * 512 + cc];
    }
    __syncthreads();
    float pa = 0.f;
#pragma unroll
    for (int m = 0; m < 8; ++m) pa += hs[row][256 + col + 32 * m] * ia_w2[col + 32 * m];
#pragma unroll
    for (int off = 16; off; off >>= 1) pa += __shfl_xor(pa, off, 64);
    if (col == 0) pas[row] = sigmf_(pa + ia_b2[0]);
    float acc = 0.f;
    for (int k = 0; k < 256; ++k) acc += hs[row][k] * ie_w2[k * 32 + col];
    __syncthreads();
    teff += eluf(acc + ie_b2[col]) * pas[row];
  }
  sa2[(size_t)(r0 + row) * 288 + 256 + col] = teff;
}

// weight concat: dst[k, 0:N]=a, dst[k, N:2N]=b  (dst is [K, 2N])
__global__ __launch_bounds__(256) void concat_w_kernel(
    const float* __restrict__ a, const float* __restrict__ b,
    float* __restrict__ dst, int N)
{
  const int idx = blockIdx.x * 256 + threadIdx.x;
  const int k = idx / (2 * N);
  const int n = idx % (2 * N);
  dst[idx] = (n < N) ? a[k * N + n] : b[k * N + (n - N)];
}

__global__ __launch_bounds__(512) void concat_b_kernel(
    const float* __restrict__ a, const float* __restrict__ b,
    float* __restrict__ dst, int N)
{
  const int t = threadIdx.x;
  dst[t] = (t < N) ? a[t] : b[t - N];
}

// dst[0:512] = src, dst[512:1024] = 0
__global__ __launch_bounds__(1024) void bias_pad_kernel(
    const float* __restrict__ src, float* __restrict__ dst)
{
  const int t = threadIdx.x;
  dst[t] = (t < 512) ? src[t] : 0.f;
}

// ---------------------------------------------------------------------------
extern "C" void kernel_launch(void* const* d_in, const int* in_sizes, int n_in,
                              void* d_out, int out_size, void* d_ws, size_t ws_size,
                              hipStream_t stream) {
  const float* samples = (const float*)d_in[0];
  const int*   action  = (const int*)d_in[1];
  // d_in[2] mask: unused by the forward pass
  const float* in_w1  = (const float*)d_in[3];
  const float* in_b1  = (const float*)d_in[4];
  const float* in_w2  = (const float*)d_in[5];
  const float* in_b2  = (const float*)d_in[6];
  const float* ae_w1  = (const float*)d_in[7];
  const float* ae_b1  = (const float*)d_in[8];
  const float* ae_w2  = (const float*)d_in[9];
  const float* ae_b2  = (const float*)d_in[10];
  const float* eff_w1 = (const float*)d_in[11];
  const float* eff_b1 = (const float*)d_in[12];
  const float* eff_w2 = (const float*)d_in[13];
  const float* eff_b2 = (const float*)d_in[14];
  const float* aat_w1 = (const float*)d_in[15];
  const float* aat_b1 = (const float*)d_in[16];
  const float* aat_w2 = (const float*)d_in[17];
  const float* aat_b2 = (const float*)d_in[18];
  const float* pw_w1  = (const float*)d_in[19];
  const float* pw_b1  = (const float*)d_in[20];
  const float* pw_w2  = (const float*)d_in[21];
  const float* pw_b2  = (const float*)d_in[22];
  const float* ie_w1  = (const float*)d_in[23];
  const float* ie_b1  = (const float*)d_in[24];
  const float* ie_w2  = (const float*)d_in[25];
  const float* ie_b2  = (const float*)d_in[26];
  const float* ia_w1  = (const float*)d_in[27];
  const float* ia_b1  = (const float*)d_in[28];
  const float* ia_w2  = (const float*)d_in[29];
  const float* ia_b2  = (const float*)d_in[30];
  const float* fm_w1  = (const float*)d_in[31];
  const float* fm_b1  = (const float*)d_in[32];
  const float* fm_w2  = (const float*)d_in[33];
  const float* fm_b2  = (const float*)d_in[34];
  const float* out_w1 = (const float*)d_in[35];
  const float* out_b1 = (const float*)d_in[36];
  const float* out_w2 = (const float*)d_in[37];
  const float* out_b2 = (const float*)d_in[38];
  float* out = (float*)d_out;

  // workspace arena (floats)
  float* ws = (float*)d_ws;
  float* sa2     = ws;                         // [8192, 288] sa / state_enc+teff / merged_in
  float* h1      = sa2     + (size_t)BLN*288;  // [8192, 256]
  float* hea     = h1      + (size_t)BLN*256;  // [8192, 512]
  float* UV      = hea     + (size_t)BLN*512;  // [8192, 1024]: cols 0:512=U, 512:1024=V
  float* pint    = UV      + (size_t)BLN*1024; // [8192, 256] merged buffer (fm phase)
  float* aenc    = pint    + (size_t)BLN*256;  // [1024, 32]
  float* satt    = aenc    + (size_t)BL*32;    // [8192]
  float* wcat_ea = satt    + BLN;              // [288, 512]
  float* bcat_ea = wcat_ea + 288*512;          // [512]
  float* wcat_ii = bcat_ea + 512;              // [256, 512]
  float* bcat_ii = wcat_ii + 256*512;          // [512]
  float* arena_end = bcat_ii + 512;
  // batched pair-phase buffers (only if workspace allows)
  float* pint_all = arena_end;                      // [7*8192, 256]
  float* hea_all  = pint_all + (size_t)7*BLN*256;   // [7*8192, 512]
  const size_t need_batched = ((size_t)63497216) * sizeof(float);
  const bool batched = (ws_size >= need_batched);
  // UV weight concat lives in the (idle until fm-phase) pint buffer
  float* wcat_pw = pint;                       // [256, 1024]
  float* bcat_pw = pint + 256*1024;            // [1024]

  const dim3 blk(256);
  const dim3 blk128(128);

  // weight prep
  concat_w_kernel<<<dim3(288*512/256), blk, 0, stream>>>(eff_w1, aat_w1, wcat_ea, 256);
  concat_b_kernel<<<dim3(1), dim3(512), 0, stream>>>(eff_b1, aat_b1, bcat_ea, 256);
  concat_w_kernel<<<dim3(256*512/256), blk, 0, stream>>>(ie_w1, ia_w1, wcat_ii, 256);
  concat_b_kernel<<<dim3(1), dim3(512), 0, stream>>>(ie_b1, ia_b1, bcat_ii, 256);
  if (batched) {
    // wcat_pw[k, 0:512] = pw_w1[k,:], [k, 512:1024] = pw_w1[256+k,:]
    concat_w_kernel<<<dim3(256*1024/256), blk, 0, stream>>>(pw_w1, pw_w1 + 256*512, wcat_pw, 512);
    bias_pad_kernel<<<dim3(1), dim3(1024), 0, stream>>>(pw_b1, bcat_pw);
  }

  // action encoder
  ae_kernel<<<dim3(BL), blk, 0, stream>>>(action, ae_w1, ae_b1, ae_w2, ae_b2, aenc);

  // in_ MLP: samples -> h1 -> sa2[:, :256]
  gemm_k<1,false,false><<<dim3(128,4), blk, 0, stream>>>(samples, 256, in_w1, 256, in_b1, h1, 256, 256, nullptr, nullptr, 0);
  gemm_k<1,false,false><<<dim3(128,4), blk, 0, stream>>>(h1, 256, in_w2, 256, in_b2, sa2, 288, 256, nullptr, nullptr, 0);
  sa_fill_kernel<<<dim3(BLN*32/256), blk, 0, stream>>>(aenc, sa2);

  // eff/aat layer1 (fused) -> hea[8192,512]  (1024 blocks — keep on gemm_k)
  gemm_k<1,false,false><<<dim3(128,8), blk, 0, stream>>>(sa2, 288, wcat_ea, 512, bcat_ea, hea, 512, 288, nullptr, nullptr, 0);
  // s_att
  satt_kernel<<<dim3(BLN/4), blk, 0, stream>>>(hea, aat_w2, aat_b2, satt);
  // eff layer2 with rowscale -> state_enc into sa2[:, :256]
  gemm_k<1,true,false><<<dim3(128,4), blk, 0, stream>>>(hea, 512, eff_w2, 256, eff_b2, sa2, 288, 256, satt, nullptr, 0);

  if (batched) {
    // UV = senc @ [pw_w1_top | pw_w1_bot] + [pw_b1 | 0]  (one fused GEMM, 512 blocks)
    gemm128_k<0,false><<<dim3(64,8), blk, 0, stream>>>(sa2, 288, wcat_pw, 1024, bcat_pw, UV, 1024, 256, nullptr);
    // pint_all = elu(elu(U[i]+V[j]) @ pw_w2 + pw_b2), all 7 jj slices (896 blocks)
    gemm16_k<1,true ><<<dim3(448,2), blk128, 0, stream>>>(UV, 1024, pw_w2, 256, pw_b2, pint_all, 256, 512, UV + 512);
    // ie/ia layer1 (fused) (1792 blocks)
    gemm16_k<1,false><<<dim3(448,4), blk128, 0, stream>>>(pint_all, 256, wcat_ii, 512, bcat_ii, hea_all, 512, 256, nullptr);
    pair_l2_all_kernel<<<dim3(BLN/8), blk, 0, stream>>>(hea_all, ie_w2, ie_b2, ia_w2, ia_b2, sa2);
  } else {
    // serial fallback: U,V into the UV layout (ldc=1024), then per-jj loop
    gemm_k<0,false,false><<<dim3(128,8), blk, 0, stream>>>(sa2, 288, pw_w1, 512, pw_b1, UV, 1024, 256, nullptr, nullptr, 0);
    gemm_k<0,false,false><<<dim3(128,8), blk, 0, stream>>>(sa2, 288, pw_w1 + 256*512, 512, nullptr, UV + 512, 1024, 256, nullptr, nullptr, 0);
    zero_teff_kernel<<<dim3(BLN*32/256), blk, 0, stream>>>(sa2);
    for (int jj = 0; jj < 7; ++jj) {
      gemm_k<1,false,true><<<dim3(128,4), blk, 0, stream>>>(UV, 1024, pw_w2, 256, pw_b2, pint, 256, 512, nullptr, UV + 512, jj);
      gemm_k<1,false,false><<<dim3(128,8), blk, 0, stream>>>(pint, 256, wcat_ii, 512, bcat_ii, hea, 512, 256, nullptr, nullptr, 0);
      pair_l2_kernel<<<dim3(BLN/8), blk, 0, stream>>>(hea, ie_w2, ie_b2, ia_w2, ia_b2, sa2);
    }
  }

  // fm MLP: sa2[8192,288] -> h1 -> merged (pint)
  gemm_k<1,false,false><<<dim3(128,4), blk, 0, stream>>>(sa2, 288, fm_w1, 256, fm_b1, h1, 256, 288, nullptr, nullptr, 0);
  gemm_k<1,false,false><<<dim3(128,4), blk, 0, stream>>>(h1, 256, fm_w2, 256, fm_b2, pint, 256, 256, nullptr, nullptr, 0);

  // out MLP: merged -> h1 -> d_out
  gemm_k<1,false,false><<<dim3(128,4), blk, 0, stream>>>(pint, 256, out_w1, 256, out_b1, h1, 256, 256, nullptr, nullptr, 0);
  gemm_k<0,false,false><<<dim3(128,4), blk, 0, stream>>>(h1, 256, out_w2, 256, out_b2, out, 256, 256, nullptr, nullptr, 0);
}

// Round 9
// 928.811 us; speedup vs baseline: 1.2428x; 1.2428x over previous
//
#include <hip/hip_runtime.h>
#include <math.h>

// ---------------------------------------------------------------------------
// OP3 Physics Network forward, fp32. Sizes: B=32,L=32,N=8,D=256,A=16,AENC=32,EFF=32
// Tokens: BLN = 8192 node tokens, pairs = 8192*7.
// Key restructure: pairs@pw_w1 = U[i]+V[j] with U=senc@W1top+b1, V=senc@W1bot.
// Round 9: restore the proven round-3 configuration (gemm128_k exact body,
// launch_bounds(256,3), VGPR 84, 290us/dispatch — rounds 4-8 bracketed it as
// a local optimum against reg-prefetch/tighter-bounds/remap/thin-block) and
// fix gemm_k's LDS STORE bank conflicts (reads were already clean):
//  - As: physical row perm phys(k)=((k&7)<<2)|(k>>3) with stride 144
//    (144===16 mod 32) -> store bank = 16(s&1)+(l>>2): 2-way = free
//    (was 4-way: stride132*8 === 0 mod 32 killed the akg term).
//  - Ws: pad 64->68 -> store chunk-starts uniform over all 8 bank-groups
//    (was collapsed onto 4 groups = 2x serialization).
// Reads use compile-time phys(k) in the unrolled loop: zero runtime cost.
// ---------------------------------------------------------------------------

#define BLN 8192
#define BL  1024

__device__ __forceinline__ float eluf(float x)  { return x > 0.0f ? x : expm1f(x); }
__device__ __forceinline__ float sigmf_(float x){ return 1.0f / (1.0f + expf(-x)); }

// physical LDS row for logical k (bank-conflict-free A staging in gemm_k)
#define APHYS(k) ((((k) & 7) << 2) | ((k) >> 3))

// ---------------------------------------------------------------------------
// Generic tiled GEMM: C[M,N] = act(A[M,K] @ W[K,N] + bias) [* rowscale[row]]
// 64x64 tile, BK=32, 256 threads, 4x4 per thread. Single-buffered LDS.
// Store-conflict-free staging (see header).
// ---------------------------------------------------------------------------
template<int ACT, bool ROWSCALE, bool PAIRGATHER>
__global__ __launch_bounds__(256) void gemm_k(
    const float* __restrict__ A, int lda,
    const float* __restrict__ W, int ldw,
    const float* __restrict__ bias,
    float* __restrict__ C, int ldc,
    int K,
    const float* __restrict__ rowscale,
    const float* __restrict__ Vm, int jj)
{
  __shared__ float As[32][144];  // physical rows = APHYS(k); stride 144 === 16 mod 32
  __shared__ float Ws[32][68];   // k-major, +4 pad for uniform store banking
  const int m0 = blockIdx.x * 64;
  const int n0 = blockIdx.y * 64;
  const int tid = threadIdx.x;

  const int arow = tid >> 2;            // 0..63
  const int s4   = tid & 3;             // k-group 0..3 (akg = s4*8)
  const int akg  = s4 << 3;
  const int wrow = tid >> 3;            // 0..31
  const int wcg  = (tid & 7) << 3;      // 0..56

  const int tr = (tid >> 4) << 2;       // 0..60
  const int tc = (tid & 15) << 2;       // 0..60

  const int gr = m0 + arow;
  const float* aptr;
  const float* vptr = nullptr;
  if (PAIRGATHER) {
    const int jjv = (jj >= 0) ? jj : (gr >> 13);
    const int r = gr & (BLN - 1);
    const int i = r & 7;
    const int j = jjv + ((jjv >= i) ? 1 : 0);
    const int vr = (r & ~7) | j;
    aptr = A  + (size_t)r * lda + akg;
    vptr = Vm + (size_t)vr * lda + akg;
  } else {
    aptr = A + (size_t)gr * lda + akg;
  }
  const float* wptr = W + (size_t)wrow * ldw + n0 + wcg;

  float acc[4][4] = {};

  for (int k0 = 0; k0 < K; k0 += 32) {
    float av[8];
    if (PAIRGATHER) {
      float4 u0 = *(const float4*)(aptr + k0);
      float4 u1 = *(const float4*)(aptr + k0 + 4);
      float4 v0 = *(const float4*)(vptr + k0);
      float4 v1 = *(const float4*)(vptr + k0 + 4);
      av[0]=eluf(u0.x+v0.x); av[1]=eluf(u0.y+v0.y); av[2]=eluf(u0.z+v0.z); av[3]=eluf(u0.w+v0.w);
      av[4]=eluf(u1.x+v1.x); av[5]=eluf(u1.y+v1.y); av[6]=eluf(u1.z+v1.z); av[7]=eluf(u1.w+v1.w);
    } else {
      float4 a0 = *(const float4*)(aptr + k0);
      float4 a1 = *(const float4*)(aptr + k0 + 4);
      av[0]=a0.x; av[1]=a0.y; av[2]=a0.z; av[3]=a0.w;
      av[4]=a1.x; av[5]=a1.y; av[6]=a1.z; av[7]=a1.w;
    }
    float4 w0 = *(const float4*)(wptr + (size_t)k0 * ldw);
    float4 w1 = *(const float4*)(wptr + (size_t)k0 * ldw + 4);

    __syncthreads();   // previous tile fully consumed before overwrite
#pragma unroll
    for (int i = 0; i < 8; ++i) As[(i << 2) | s4][arow] = av[i];  // phys(akg+i)
    *(float4*)&Ws[wrow][wcg]     = w0;
    *(float4*)&Ws[wrow][wcg + 4] = w1;
    __syncthreads();

#pragma unroll
    for (int k = 0; k < 32; ++k) {
      float4 a = *(const float4*)&As[APHYS(k)][tr];
      float4 w = *(const float4*)&Ws[k][tc];
      acc[0][0] += a.x*w.x; acc[0][1] += a.x*w.y; acc[0][2] += a.x*w.z; acc[0][3] += a.x*w.w;
      acc[1][0] += a.y*w.x; acc[1][1] += a.y*w.y; acc[1][2] += a.y*w.z; acc[1][3] += a.y*w.w;
      acc[2][0] += a.z*w.x; acc[2][1] += a.z*w.y; acc[2][2] += a.z*w.z; acc[2][3] += a.z*w.w;
      acc[3][0] += a.w*w.x; acc[3][1] += a.w*w.y; acc[3][2] += a.w*w.z; acc[3][3] += a.w*w.w;
    }
  }

  float bv[4] = {0.f, 0.f, 0.f, 0.f};
  if (bias) {
    float4 b = *(const float4*)(bias + n0 + tc);
    bv[0]=b.x; bv[1]=b.y; bv[2]=b.z; bv[3]=b.w;
  }
#pragma unroll
  for (int i = 0; i < 4; ++i) {
    const int r = m0 + tr + i;
    float v0 = acc[i][0] + bv[0];
    float v1 = acc[i][1] + bv[1];
    float v2 = acc[i][2] + bv[2];
    float v3 = acc[i][3] + bv[3];
    if (ACT == 1) { v0=eluf(v0); v1=eluf(v1); v2=eluf(v2); v3=eluf(v3); }
    else if (ACT == 2) { v0=sigmf_(v0); v1=sigmf_(v1); v2=sigmf_(v2); v3=sigmf_(v3); }
    if (ROWSCALE) { float s = rowscale[r]; v0*=s; v1*=s; v2*=s; v3*=s; }
    float4 o; o.x=v0; o.y=v1; o.z=v2; o.w=v3;
    *(float4*)&C[(size_t)r * ldc + n0 + tc] = o;
  }
}

// ---------------------------------------------------------------------------
// Big GEMM (UV, pint, ie/ia): 128x128 tile, BK=32, 256 threads, 8x8/thread.
// EXACT ROUND-3 BODY (proven VGPR=84, no spill, 290us): loads at loop top
// before barrier-1, nothing held across the FMA block. launch_bounds(256,3).
// Store banking already clean (As 2-way free, Ws uniform 8/group).
// PAIRGATHER: A_virtual[r,k] = elu(U[r,k] + V[vrow(r),k]); jj from row>>13.
// ---------------------------------------------------------------------------
template<int ACT, bool PAIRGATHER>
__global__ __launch_bounds__(256, 3) void gemm128_k(
    const float* __restrict__ A, int lda,
    const float* __restrict__ W, int ldw,
    const float* __restrict__ bias,
    float* __restrict__ C, int ldc,
    int K,
    const float* __restrict__ Vm)
{
  __shared__ float As[32][132];
  __shared__ float Ws[32][132];
  const int m0 = blockIdx.x * 128;
  const int n0 = blockIdx.y * 128;
  const int tid = threadIdx.x;

  const int arow = tid >> 1;            // 0..127
  const int ak16 = (tid & 1) << 4;      // 0,16
  const int wrow = tid >> 3;            // 0..31
  const int wcg  = (tid & 7) << 4;      // 0..112

  const int ty4 = (tid >> 4) << 2;      // 0..60
  const int tx4 = (tid & 15) << 2;      // 0..60

  const int gr = m0 + arow;
  const float* aptr;
  const float* vptr = nullptr;
  if (PAIRGATHER) {
    const int jjv = gr >> 13;
    const int r = gr & (BLN - 1);
    const int i = r & 7;
    const int j = jjv + ((jjv >= i) ? 1 : 0);
    const int vr = (r & ~7) | j;
    aptr = A  + (size_t)r * lda + ak16;
    vptr = Vm + (size_t)vr * lda + ak16;
  } else {
    aptr = A + (size_t)gr * lda + ak16;
  }
  const float* wptr = W + (size_t)wrow * ldw + n0 + wcg;

  float acc[8][8] = {};

  for (int k0 = 0; k0 < K; k0 += 32) {
    // issue global loads before the barrier (overlap with other waves)
    float4 ua[4], va[4], wa[4];
#pragma unroll
    for (int q = 0; q < 4; ++q) ua[q] = *(const float4*)(aptr + k0 + 4*q);
    if (PAIRGATHER) {
#pragma unroll
      for (int q = 0; q < 4; ++q) va[q] = *(const float4*)(vptr + k0 + 4*q);
    }
#pragma unroll
    for (int q = 0; q < 4; ++q) wa[q] = *(const float4*)(wptr + (size_t)k0 * ldw + 4*q);

    __syncthreads();   // previous tile fully consumed before overwrite
#pragma unroll
    for (int q = 0; q < 4; ++q) {
      float4 u = ua[q];
      if (PAIRGATHER) {
        float4 v = va[q];
        u.x = eluf(u.x+v.x); u.y = eluf(u.y+v.y); u.z = eluf(u.z+v.z); u.w = eluf(u.w+v.w);
      }
      As[ak16 + 4*q + 0][arow] = u.x;
      As[ak16 + 4*q + 1][arow] = u.y;
      As[ak16 + 4*q + 2][arow] = u.z;
      As[ak16 + 4*q + 3][arow] = u.w;
    }
#pragma unroll
    for (int q = 0; q < 4; ++q)
      *(float4*)&Ws[wrow][wcg + 4*q] = wa[q];
    __syncthreads();

#pragma unroll
    for (int k = 0; k < 32; ++k) {
      float4 a0 = *(const float4*)&As[k][ty4];
      float4 a1 = *(const float4*)&As[k][64 + ty4];
      float4 w0 = *(const float4*)&Ws[k][tx4];
      float4 w1 = *(const float4*)&Ws[k][64 + tx4];
      float ar[8] = {a0.x,a0.y,a0.z,a0.w,a1.x,a1.y,a1.z,a1.w};
      float wr[8] = {w0.x,w0.y,w0.z,w0.w,w1.x,w1.y,w1.z,w1.w};
#pragma unroll
      for (int i = 0; i < 8; ++i) {
#pragma unroll
        for (int j = 0; j < 8; ++j) acc[i][j] += ar[i] * wr[j];
      }
    }
  }

  float bv[8] = {0.f,0.f,0.f,0.f,0.f,0.f,0.f,0.f};
  if (bias) {
    float4 b0 = *(const float4*)(bias + n0 + tx4);
    float4 b1 = *(const float4*)(bias + n0 + 64 + tx4);
    bv[0]=b0.x; bv[1]=b0.y; bv[2]=b0.z; bv[3]=b0.w;
    bv[4]=b1.x; bv[5]=b1.y; bv[6]=b1.z; bv[7]=b1.w;
  }
#pragma unroll
  for (int ih = 0; ih < 2; ++ih) {
#pragma unroll
    for (int i = 0; i < 4; ++i) {
      const int r = m0 + ih*64 + ty4 + i;
#pragma unroll
      for (int jh = 0; jh < 2; ++jh) {
        float v0 = acc[ih*4+i][jh*4+0] + bv[jh*4+0];
        float v1 = acc[ih*4+i][jh*4+1] + bv[jh*4+1];
        float v2 = acc[ih*4+i][jh*4+2] + bv[jh*4+2];
        float v3 = acc[ih*4+i][jh*4+3] + bv[jh*4+3];
        if (ACT == 1) { v0=eluf(v0); v1=eluf(v1); v2=eluf(v2); v3=eluf(v3); }
        else if (ACT == 2) { v0=sigmf_(v0); v1=sigmf_(v1); v2=sigmf_(v2); v3=sigmf_(v3); }
        float4 o; o.x=v0; o.y=v1; o.z=v2; o.w=v3;
        *(float4*)&C[(size_t)r * ldc + n0 + jh*64 + tx4] = o;
      }
    }
  }
}

// ---------------------------------------------------------------------------
// Action-encoder MLP: one block per (b,l) token. one_hot @ w1 == w1[a].
// ---------------------------------------------------------------------------
__global__ __launch_bounds__(256) void ae_kernel(
    const int* __restrict__ action,
    const float* __restrict__ w1, const float* __restrict__ b1,
    const float* __restrict__ w2, const float* __restrict__ b2,
    float* __restrict__ aenc)
{
  __shared__ float hs[256];
  const int bl = blockIdx.x;
  const int t = threadIdx.x;
  const int a = action[bl];
  hs[t] = eluf(w1[a * 256 + t] + b1[t]);
  __syncthreads();
  if (t < 32) {
    float acc = 0.f;
    for (int k = 0; k < 256; ++k) acc += hs[k] * w2[k * 32 + t];
    aenc[bl * 32 + t] = eluf(acc + b2[t]);
  }
}

// fill sa2[:, 256:288] with broadcast aenc
__global__ __launch_bounds__(256) void sa_fill_kernel(const float* __restrict__ aenc,
                                                      float* __restrict__ sa2)
{
  const int idx = blockIdx.x * 256 + threadIdx.x;  // 8192*32
  const int r = idx >> 5, c = idx & 31;
  sa2[(size_t)r * 288 + 256 + c] = aenc[(r >> 3) * 32 + c];
}

// zero sa2[:, 256:288] (serial fallback path only)
__global__ __launch_bounds__(256) void zero_teff_kernel(float* __restrict__ sa2)
{
  const int idx = blockIdx.x * 256 + threadIdx.x;
  const int r = idx >> 5, c = idx & 31;
  sa2[(size_t)r * 288 + 256 + c] = 0.f;
}

// s_att[row] = sigmoid(dot(h_ea[row,256:512], aat_w2) + aat_b2). 4 rows/block.
__global__ __launch_bounds__(256) void satt_kernel(
    const float* __restrict__ hea, const float* __restrict__ w,
    const float* __restrict__ b, float* __restrict__ satt)
{
  const int wv = threadIdx.x >> 6;
  const int lane = threadIdx.x & 63;
  const int row = blockIdx.x * 4 + wv;
  const float* h = hea + (size_t)row * 512 + 256;
  float acc = 0.f;
#pragma unroll
  for (int m = 0; m < 4; ++m) acc += h[lane + 64 * m] * w[lane + 64 * m];
#pragma unroll
  for (int off = 32; off; off >>= 1) acc += __shfl_xor(acc, off, 64);
  if (lane == 0) satt[row] = sigmf_(acc + b[0]);
}

// ie/ia layer-2 + p_eff*p_att + accumulate (serial fallback). 8 rows/block.
__global__ __launch_bounds__(256) void pair_l2_kernel(
    const float* __restrict__ h,
    const float* __restrict__ ie_w2, const float* __restrict__ ie_b2,
    const float* __restrict__ ia_w2, const float* __restrict__ ia_b2,
    float* __restrict__ sa2)
{
  __shared__ float hs[8][512];
  __shared__ float pas[8];
  const int r0 = blockIdx.x * 8;
  const int tid = threadIdx.x;
#pragma unroll
  for (int it = 0; it < 4; ++it) {
    const int f4 = it * 256 + tid;
    const int rr = f4 >> 7;
    const int cc = (f4 & 127) << 2;
    *(float4*)&hs[rr][cc] = *(const float4*)&h[(size_t)(r0 + rr) * 512 + cc];
  }
  __syncthreads();
  const int row = tid >> 5;
  const int col = tid & 31;
  float pa = 0.f;
#pragma unroll
  for (int m = 0; m < 8; ++m) pa += hs[row][256 + col + 32 * m] * ia_w2[col + 32 * m];
#pragma unroll
  for (int off = 16; off; off >>= 1) pa += __shfl_xor(pa, off, 64);
  if (col == 0) pas[row] = sigmf_(pa + ia_b2[0]);
  float acc = 0.f;
  for (int k = 0; k < 256; ++k) acc += hs[row][k] * ie_w2[k * 32 + col];
  __syncthreads();
  const float val = eluf(acc + ie_b2[col]) * pas[row];
  sa2[(size_t)(r0 + row) * 288 + 256 + col] += val;
}

// Batched variant: h is [7*8192, 512]; loop jj internally, accumulate in regs.
__global__ __launch_bounds__(256) void pair_l2_all_kernel(
    const float* __restrict__ h,
    const float* __restrict__ ie_w2, const float* __restrict__ ie_b2,
    const float* __restrict__ ia_w2, const float* __restrict__ ia_b2,
    float* __restrict__ sa2)
{
  __shared__ float hs[8][512];
  __shared__ float pas[8];
  const int r0 = blockIdx.x * 8;
  const int tid = threadIdx.x;
  const int row = tid >> 5;
  const int col = tid & 31;
  float teff = 0.f;
  for (int jj = 0; jj < 7; ++jj) {
    __syncthreads();
    const float* hb = h + ((size_t)jj * BLN + r0) * 512;
#pragma unroll
    for (int it = 0; it < 4; ++it) {
      const int f4 = it * 256 + tid;
      const int rr = f4 >> 7;
      const int cc = (f4 & 127) << 2;
      *(float4*)&hs[rr][cc] = *(const float4*)&hb[(size_t)rr * 512 + cc];
    }
    __syncthreads();
    float pa = 0.f;
#pragma unroll
    for (int m = 0; m < 8; ++m) pa += hs[row][256 + col + 32 * m] * ia_w2[col + 32 * m];
#pragma unroll
    for (int off = 16; off; off >>= 1) pa += __shfl_xor(pa, off, 64);
    if (col == 0) pas[row] = sigmf_(pa + ia_b2[0]);
    float acc = 0.f;
    for (int k = 0; k < 256; ++k) acc += hs[row][k] * ie_w2[k * 32 + col];
    __syncthreads();
    teff += eluf(acc + ie_b2[col]) * pas[row];
  }
  sa2[(size_t)(r0 + row) * 288 + 256 + col] = teff;
}

// weight concat: dst[k, 0:N]=a, dst[k, N:2N]=b  (dst is [K, 2N])
__global__ __launch_bounds__(256) void concat_w_kernel(
    const float* __restrict__ a, const float* __restrict__ b,
    float* __restrict__ dst, int N)
{
  const int idx = blockIdx.x * 256 + threadIdx.x;
  const int k = idx / (2 * N);
  const int n = idx % (2 * N);
  dst[idx] = (n < N) ? a[k * N + n] : b[k * N + (n - N)];
}

__global__ __launch_bounds__(512) void concat_b_kernel(
    const float* __restrict__ a, const float* __restrict__ b,
    float* __restrict__ dst, int N)
{
  const int t = threadIdx.x;
  dst[t] = (t < N) ? a[t] : b[t - N];
}

// dst[0:512] = src, dst[512:1024] = 0
__global__ __launch_bounds__(1024) void bias_pad_kernel(
    const float* __restrict__ src, float* __restrict__ dst)
{
  const int t = threadIdx.x;
  dst[t] = (t < 512) ? src[t] : 0.f;
}

// ---------------------------------------------------------------------------
extern "C" void kernel_launch(void* const* d_in, const int* in_sizes, int n_in,
                              void* d_out, int out_size, void* d_ws, size_t ws_size,
                              hipStream_t stream) {
  const float* samples = (const float*)d_in[0];
  const int*   action  = (const int*)d_in[1];
  // d_in[2] mask: unused by the forward pass
  const float* in_w1  = (const float*)d_in[3];
  const float* in_b1  = (const float*)d_in[4];
  const float* in_w2  = (const float*)d_in[5];
  const float* in_b2  = (const float*)d_in[6];
  const float* ae_w1  = (const float*)d_in[7];
  const float* ae_b1  = (const float*)d_in[8];
  const float* ae_w2  = (const float*)d_in[9];
  const float* ae_b2  = (const float*)d_in[10];
  const float* eff_w1 = (const float*)d_in[11];
  const float* eff_b1 = (const float*)d_in[12];
  const float* eff_w2 = (const float*)d_in[13];
  const float* eff_b2 = (const float*)d_in[14];
  const float* aat_w1 = (const float*)d_in[15];
  const float* aat_b1 = (const float*)d_in[16];
  const float* aat_w2 = (const float*)d_in[17];
  const float* aat_b2 = (const float*)d_in[18];
  const float* pw_w1  = (const float*)d_in[19];
  const float* pw_b1  = (const float*)d_in[20];
  const float* pw_w2  = (const float*)d_in[21];
  const float* pw_b2  = (const float*)d_in[22];
  const float* ie_w1  = (const float*)d_in[23];
  const float* ie_b1  = (const float*)d_in[24];
  const float* ie_w2  = (const float*)d_in[25];
  const float* ie_b2  = (const float*)d_in[26];
  const float* ia_w1  = (const float*)d_in[27];
  const float* ia_b1  = (const float*)d_in[28];
  const float* ia_w2  = (const float*)d_in[29];
  const float* ia_b2  = (const float*)d_in[30];
  const float* fm_w1  = (const float*)d_in[31];
  const float* fm_b1  = (const float*)d_in[32];
  const float* fm_w2  = (const float*)d_in[33];
  const float* fm_b2  = (const float*)d_in[34];
  const float* out_w1 = (const float*)d_in[35];
  const float* out_b1 = (const float*)d_in[36];
  const float* out_w2 = (const float*)d_in[37];
  const float* out_b2 = (const float*)d_in[38];
  float* out = (float*)d_out;

  // workspace arena (floats)
  float* ws = (float*)d_ws;
  float* sa2     = ws;                         // [8192, 288] sa / state_enc+teff / merged_in
  float* h1      = sa2     + (size_t)BLN*288;  // [8192, 256]
  float* hea     = h1      + (size_t)BLN*256;  // [8192, 512]
  float* UV      = hea     + (size_t)BLN*512;  // [8192, 1024]: cols 0:512=U, 512:1024=V
  float* pint    = UV      + (size_t)BLN*1024; // [8192, 256] merged buffer (fm phase)
  float* aenc    = pint    + (size_t)BLN*256;  // [1024, 32]
  float* satt    = aenc    + (size_t)BL*32;    // [8192]
  float* wcat_ea = satt    + BLN;              // [288, 512]
  float* bcat_ea = wcat_ea + 288*512;          // [512]
  float* wcat_ii = bcat_ea + 512;              // [256, 512]
  float* bcat_ii = wcat_ii + 256*512;          // [512]
  float* arena_end = bcat_ii + 512;
  // batched pair-phase buffers (only if workspace allows)
  float* pint_all = arena_end;                      // [7*8192, 256]
  float* hea_all  = pint_all + (size_t)7*BLN*256;   // [7*8192, 512]
  const size_t need_batched = ((size_t)63497216) * sizeof(float);
  const bool batched = (ws_size >= need_batched);
  // UV weight concat lives in the (idle until fm-phase) pint buffer
  float* wcat_pw = pint;                       // [256, 1024]
  float* bcat_pw = pint + 256*1024;            // [1024]

  const dim3 blk(256);

  // weight prep
  concat_w_kernel<<<dim3(288*512/256), blk, 0, stream>>>(eff_w1, aat_w1, wcat_ea, 256);
  concat_b_kernel<<<dim3(1), dim3(512), 0, stream>>>(eff_b1, aat_b1, bcat_ea, 256);
  concat_w_kernel<<<dim3(256*512/256), blk, 0, stream>>>(ie_w1, ia_w1, wcat_ii, 256);
  concat_b_kernel<<<dim3(1), dim3(512), 0, stream>>>(ie_b1, ia_b1, bcat_ii, 256);
  if (batched) {
    // wcat_pw[k, 0:512] = pw_w1[k,:], [k, 512:1024] = pw_w1[256+k,:]
    concat_w_kernel<<<dim3(256*1024/256), blk, 0, stream>>>(pw_w1, pw_w1 + 256*512, wcat_pw, 512);
    bias_pad_kernel<<<dim3(1), dim3(1024), 0, stream>>>(pw_b1, bcat_pw);
  }

  // action encoder
  ae_kernel<<<dim3(BL), blk, 0, stream>>>(action, ae_w1, ae_b1, ae_w2, ae_b2, aenc);

  // in_ MLP: samples -> h1 -> sa2[:, :256]
  gemm_k<1,false,false><<<dim3(128,4), blk, 0, stream>>>(samples, 256, in_w1, 256, in_b1, h1, 256, 256, nullptr, nullptr, 0);
  gemm_k<1,false,false><<<dim3(128,4), blk, 0, stream>>>(h1, 256, in_w2, 256, in_b2, sa2, 288, 256, nullptr, nullptr, 0);
  sa_fill_kernel<<<dim3(BLN*32/256), blk, 0, stream>>>(aenc, sa2);

  // eff/aat layer1 (fused) -> hea[8192,512]  (1024 blocks — keep on gemm_k)
  gemm_k<1,false,false><<<dim3(128,8), blk, 0, stream>>>(sa2, 288, wcat_ea, 512, bcat_ea, hea, 512, 288, nullptr, nullptr, 0);
  // s_att
  satt_kernel<<<dim3(BLN/4), blk, 0, stream>>>(hea, aat_w2, aat_b2, satt);
  // eff layer2 with rowscale -> state_enc into sa2[:, :256]
  gemm_k<1,true,false><<<dim3(128,4), blk, 0, stream>>>(hea, 512, eff_w2, 256, eff_b2, sa2, 288, 256, satt, nullptr, 0);

  if (batched) {
    // UV = senc @ [pw_w1_top | pw_w1_bot] + [pw_b1 | 0]  (one fused GEMM, 512 blocks)
    gemm128_k<0,false><<<dim3(64,8), blk, 0, stream>>>(sa2, 288, wcat_pw, 1024, bcat_pw, UV, 1024, 256, nullptr);
    // pint_all = elu(elu(U[i]+V[j]) @ pw_w2 + pw_b2), all 7 jj slices (896 blocks)
    gemm128_k<1,true ><<<dim3(448,2), blk, 0, stream>>>(UV, 1024, pw_w2, 256, pw_b2, pint_all, 256, 512, UV + 512);
    // ie/ia layer1 (fused) (1792 blocks)
    gemm128_k<1,false><<<dim3(448,4), blk, 0, stream>>>(pint_all, 256, wcat_ii, 512, bcat_ii, hea_all, 512, 256, nullptr);
    pair_l2_all_kernel<<<dim3(BLN/8), blk, 0, stream>>>(hea_all, ie_w2, ie_b2, ia_w2, ia_b2, sa2);
  } else {
    // serial fallback: U,V into the UV layout (ldc=1024), then per-jj loop
    gemm_k<0,false,false><<<dim3(128,8), blk, 0, stream>>>(sa2, 288, pw_w1, 512, pw_b1, UV, 1024, 256, nullptr, nullptr, 0);
    gemm_k<0,false,false><<<dim3(128,8), blk, 0, stream>>>(sa2, 288, pw_w1 + 256*512, 512, nullptr, UV + 512, 1024, 256, nullptr, nullptr, 0);
    zero_teff_kernel<<<dim3(BLN*32/256), blk, 0, stream>>>(sa2);
    for (int jj = 0; jj < 7; ++jj) {
      gemm_k<1,false,true><<<dim3(128,4), blk, 0, stream>>>(UV, 1024, pw_w2, 256, pw_b2, pint, 256, 512, nullptr, UV + 512, jj);
      gemm_k<1,false,false><<<dim3(128,8), blk, 0, stream>>>(pint, 256, wcat_ii, 512, bcat_ii, hea, 512, 256, nullptr, nullptr, 0);
      pair_l2_kernel<<<dim3(BLN/8), blk, 0, stream>>>(hea, ie_w2, ie_b2, ia_w2, ia_b2, sa2);
    }
  }

  // fm MLP: sa2[8192,288] -> h1 -> merged (pint)
  gemm_k<1,false,false><<<dim3(128,4), blk, 0, stream>>>(sa2, 288, fm_w1, 256, fm_b1, h1, 256, 288, nullptr, nullptr, 0);
  gemm_k<1,false,false><<<dim3(128,4), blk, 0, stream>>>(h1, 256, fm_w2, 256, fm_b2, pint, 256, 256, nullptr, nullptr, 0);

  // out MLP: merged -> h1 -> d_out
  gemm_k<1,false,false><<<dim3(128,4), blk, 0, stream>>>(pint, 256, out_w1, 256, out_b1, h1, 256, 256, nullptr, nullptr, 0);
  gemm_k<0,false,false><<<dim3(128,4), blk, 0, stream>>>(h1, 256, out_w2, 256, out_b2, out, 256, 256, nullptr, nullptr, 0);
}